// Round 3
// baseline (281.828 us; speedup 1.0000x reference)
//
#include <hip/hip_runtime.h>
#include <hip/hip_bf16.h>
#include <math.h>

// Problem sizes (fixed by the reference)
#define BQ   8
#define SEQ  2048
#define DV   512
#define DA   512
#define MTOT (BQ * SEQ)   // 16384

typedef __attribute__((ext_vector_type(8))) short bf16x8;
typedef __attribute__((ext_vector_type(4))) float f32x4;
typedef __attribute__((ext_vector_type(4))) short short4v;

__device__ __forceinline__ unsigned short f2bf(float f) {
    union { float f; unsigned u; } c; c.f = f;
    unsigned u = c.u;
    unsigned r = (u + 0x7fffu + ((u >> 16) & 1u)) >> 16;
    return (unsigned short)r;
}
__device__ __forceinline__ float bf2f(unsigned short h) {
    union { unsigned u; float f; } c; c.u = ((unsigned)h) << 16;
    return c.f;
}

__device__ __forceinline__ void gload_lds16(const void* g, void* l) {
    __builtin_amdgcn_global_load_lds(
        (const __attribute__((address_space(1))) void*)g,
        (__attribute__((address_space(3))) void*)l,
        16, 0, 0);
}

// inline-asm LDS read: opaque to the compiler's waitcnt insertion, so no
// conservative vmcnt(0) drain is emitted against in-flight global_load_lds.
__device__ __forceinline__ bf16x8 dsr128(const short* p) {
    bf16x8 r;
    asm volatile("ds_read_b128 %0, %1"
                 : "=v"(r)
                 : "v"((const __attribute__((address_space(3))) short*)p));
    return r;
}

__device__ __forceinline__ void barx() {
    __builtin_amdgcn_sched_barrier(0);
    __builtin_amdgcn_s_barrier();
    __builtin_amdgcn_sched_barrier(0);
}

// ---------------- convert f32 -> bf16 (vectorized) ----------------
__global__ __launch_bounds__(256) void cvt_f32_bf16(
    const float* __restrict__ in, short* __restrict__ out, int n4)
{
    int i = blockIdx.x * blockDim.x + threadIdx.x;
    int stride = gridDim.x * blockDim.x;
    for (; i < n4; i += stride) {
        float4 v = ((const float4*)in)[i];
        short4v o;
        o[0] = (short)f2bf(v.x);
        o[1] = (short)f2bf(v.y);
        o[2] = (short)f2bf(v.z);
        o[3] = (short)f2bf(v.w);
        ((short4v*)out)[i] = o;
    }
}

// =====================================================================
// 256x256x(BK=64) 8-phase bf16 GEMM (T2 swizzle + T3/T4 counted vmcnt + T5)
// C[M,N] = A[M,K] * B[N,K]^T, fp32 accum. 512 threads = 8 waves (2Mx4N),
// per-wave 128x64 output = acc[8][4] of 16x16 frags. LDS 128 KB.
// ds-reads are inline-asm (rule #18 pattern): manual lgkmcnt(0)+sched_barrier.
// OMODE 0: bf16 C row-major (batched)     [scores]
// OMODE 1: f32  C row-major (batched)     [PV -> d_out]
// OMODE 3: fused QKV epilogue: col<512 -> Q (scaled), <1024 -> K, else V^T
// =====================================================================
template<int OMODE>
__global__ __launch_bounds__(512, 2) void gemm256(
    const short* __restrict__ A, const short* __restrict__ B, void* __restrict__ Cv,
    int ntx, int K, int lda, int ldb, int ldc,
    long strideA, long strideB, long strideC, float scale)
{
    extern __shared__ short lds[];
    short* const bufA0 = lds;
    short* const bufA1 = lds + 16384;
    short* const bufB0 = lds + 32768;
    short* const bufB1 = lds + 49152;

    const int tid  = threadIdx.x;
    const int lane = tid & 63;
    const int wv   = tid >> 6;
    const int wr   = wv >> 2;    // 0..1
    const int wc   = wv & 3;     // 0..3
    const int r16  = lane & 15;
    const int kq   = lane >> 4;  // 0..3
    const int swz  = (r16 & 7) * 8;                 // shorts (== 16B-granule XOR)
    const int cs[2] = { (kq * 8) ^ swz, (32 + kq * 8) ^ swz };
    const int aOff = (wr * 128 + r16) * 64;         // shorts into A tile
    const int bOff = (wc * 64  + r16) * 64;         // shorts into B tile

    // bijective XCD swizzle (m204)
    const int nwg = gridDim.x;
    const int wg  = blockIdx.x;
    const int q8  = nwg >> 3, r8 = nwg & 7;
    const int xcd = wg & 7, off8 = wg >> 3;
    const int swg = (xcd < r8 ? xcd * (q8 + 1) : r8 * (q8 + 1) + (xcd - r8) * q8) + off8;
    const int tx = swg % ntx, ty = swg / ntx;
    const int brow = ty * 256, bcol = tx * 256;
    const int z = blockIdx.z;

    A += (size_t)z * strideA + (size_t)brow * lda;
    B += (size_t)z * strideB + (size_t)bcol * ldb;

    // stage one half-tile (128 rows x 64 cols bf16 = 16KB) : 2 loads/thread
    auto stageHalf = [&](const short* gbase, int ld, short* region, int h) {
        #pragma unroll
        for (int c = 0; c < 2; ++c) {
            int s    = h * 1024 + c * 512 + tid;   // 16B slot index 0..2047
            int row  = s >> 3;
            int chnk = (s & 7) ^ (row & 7);        // inverse-swizzled source
            gload_lds16(gbase + (size_t)row * ld + chnk * 8, region + s * 8);
        }
    };

    f32x4 acc[8][4];
    const f32x4 fz = {0.f, 0.f, 0.f, 0.f};
    #pragma unroll
    for (int i = 0; i < 8; ++i)
        #pragma unroll
        for (int j = 0; j < 4; ++j) acc[i][j] = fz;

    bf16x8 af[4][2], bfr[4][2];

    auto dsA = [&](const short* base, int ibase) {
        #pragma unroll
        for (int i = 0; i < 4; ++i)
            #pragma unroll
            for (int kk = 0; kk < 2; ++kk)
                af[i][kk] = dsr128(base + aOff + (ibase + i) * 1024 + cs[kk]);
    };
    auto dsB = [&](const short* base, int jbase) {
        #pragma unroll
        for (int j = 0; j < 2; ++j)
            #pragma unroll
            for (int kk = 0; kk < 2; ++kk)
                bfr[jbase + j][kk] = dsr128(base + bOff + (jbase + j) * 1024 + cs[kk]);
    };
    auto doQ = [&](int ibase, int jbase) {
        __builtin_amdgcn_s_setprio(1);
        #pragma unroll
        for (int i = 0; i < 4; ++i)
            #pragma unroll
            for (int j = 0; j < 2; ++j)
                #pragma unroll
                for (int kk = 0; kk < 2; ++kk)
                    acc[ibase + i][jbase + j] = __builtin_amdgcn_mfma_f32_16x16x32_bf16(
                        af[i][kk], bfr[jbase + j][kk], acc[ibase + i][jbase + j], 0, 0, 0);
        __builtin_amdgcn_s_setprio(0);
    };

    const int NT = K >> 6;   // K-tiles of 64 (NT even, >= 4 for all our shapes)

    // ---- prologue: B(0), A(0), B(1) staged; keep B(1) in flight
    stageHalf(B,      ldb, bufB0, 0);  stageHalf(B,      ldb, bufB0, 1);
    stageHalf(A,      lda, bufA0, 0);  stageHalf(A,      lda, bufA0, 1);
    stageHalf(B + 64, ldb, bufB1, 0);  stageHalf(B + 64, ldb, bufB1, 1);
    asm volatile("s_waitcnt vmcnt(4)" ::: "memory");
    barx();

    for (int t = 0; t < NT; t += 2) {
        const bool s2 = (t + 2) < NT;      // tile t+2 exists
        const bool s3 = (t + 3) < NT;      // tile t+3 exists
        const short* At1 = A + (t + 1) * 64;
        const short* At2 = A + (t + 2) * 64;
        const short* Bt2 = B + (t + 2) * 64;
        const short* Bt3 = B + (t + 3) * 64;

        // ph1: Q0 of tile t (m0-3 x n0-1)
        dsA(bufA0, 0); dsB(bufB0, 0);
        stageHalf(At1, lda, bufA1, 0);
        barx();
        asm volatile("s_waitcnt lgkmcnt(0)" ::: "memory");
        __builtin_amdgcn_sched_barrier(0);
        doQ(0, 0);
        barx();

        // ph2: Q1 (m0-3 x n2-3)
        dsB(bufB0, 2);
        stageHalf(At1, lda, bufA1, 1);
        barx();
        asm volatile("s_waitcnt lgkmcnt(0)" ::: "memory");
        __builtin_amdgcn_sched_barrier(0);
        doQ(0, 2);
        barx();

        // ph3: Q2 (m4-7 x n0-1)
        dsA(bufA0, 4);
        if (s2) stageHalf(Bt2, ldb, bufB0, 0);
        barx();
        asm volatile("s_waitcnt lgkmcnt(0)" ::: "memory");
        __builtin_amdgcn_sched_barrier(0);
        doQ(4, 0);
        barx();

        // ph4: Q3 (m4-7 x n2-3); counted vmcnt
        if (s2) stageHalf(Bt2, ldb, bufB0, 1);
        if (s2) asm volatile("s_waitcnt vmcnt(4)" ::: "memory");
        else    asm volatile("s_waitcnt vmcnt(0)" ::: "memory");
        barx();
        doQ(4, 2);
        barx();

        // ph5: tile t+1, Q0
        dsA(bufA1, 0); dsB(bufB1, 0);
        if (s2) stageHalf(At2, lda, bufA0, 0);
        barx();
        asm volatile("s_waitcnt lgkmcnt(0)" ::: "memory");
        __builtin_amdgcn_sched_barrier(0);
        doQ(0, 0);
        barx();

        // ph6: Q1
        dsB(bufB1, 2);
        if (s2) stageHalf(At2, lda, bufA0, 1);
        barx();
        asm volatile("s_waitcnt lgkmcnt(0)" ::: "memory");
        __builtin_amdgcn_sched_barrier(0);
        doQ(0, 2);
        barx();

        // ph7: Q2
        dsA(bufA1, 4);
        if (s3) stageHalf(Bt3, ldb, bufB1, 0);
        barx();
        asm volatile("s_waitcnt lgkmcnt(0)" ::: "memory");
        __builtin_amdgcn_sched_barrier(0);
        doQ(4, 0);
        barx();

        // ph8: Q3; counted vmcnt
        if (s3) stageHalf(Bt3, ldb, bufB1, 1);
        if (s3) asm volatile("s_waitcnt vmcnt(4)" ::: "memory");
        else    asm volatile("s_waitcnt vmcnt(0)" ::: "memory");
        barx();
        doQ(4, 2);
        barx();
    }

    // ---- epilogue
    const int orow = (lane >> 4) * 4;
    #pragma unroll
    for (int i = 0; i < 8; ++i) {
        int grow = brow + wr * 128 + i * 16 + orow;
        #pragma unroll
        for (int j = 0; j < 4; ++j) {
            int gcol = bcol + wc * 64 + j * 16 + r16;
            f32x4 v = acc[i][j];
            #pragma unroll
            for (int tt = 0; tt < 4; ++tt) {
                int row = grow + tt;
                if (OMODE == 0) {
                    ((short*)Cv)[(size_t)z * strideC + (size_t)row * ldc + gcol] =
                        (short)f2bf(v[tt] * scale);
                } else if (OMODE == 1) {
                    ((float*)Cv)[(size_t)z * strideC + (size_t)row * ldc + gcol] = v[tt];
                } else { // OMODE 3: fused QKV
                    short* Qb = (short*)Cv;
                    short* Kb = Qb + (size_t)MTOT * DA;
                    short* VT = Kb + (size_t)MTOT * DA;
                    if (gcol < 512) {
                        Qb[(size_t)row * DA + gcol] = (short)f2bf(v[tt] * scale);
                    } else if (gcol < 1024) {
                        Kb[(size_t)row * DA + (gcol - 512)] = (short)f2bf(v[tt]);
                    } else {
                        int vcol = gcol - 1024;
                        int bb = row >> 11, ss = row & (SEQ - 1);
                        VT[((size_t)bb * DV + vcol) * SEQ + ss] = (short)f2bf(v[tt]);
                    }
                }
            }
        }
    }
}

// ---------------- row softmax over 2048 bf16, in place, 1 wave / row ------
__global__ __launch_bounds__(256) void softmax_rows(short* __restrict__ S)
{
    int row  = blockIdx.x * 4 + (threadIdx.x >> 6);
    int lane = threadIdx.x & 63;
    size_t base = (size_t)row * SEQ;

    float v[32];
    #pragma unroll
    for (int c = 0; c < 4; ++c) {
        bf16x8 x = *(const bf16x8*)&S[base + c * 512 + lane * 8];
        #pragma unroll
        for (int e = 0; e < 8; ++e) v[c * 8 + e] = bf2f((unsigned short)x[e]);
    }
    float mx = -1e30f;
    #pragma unroll
    for (int i = 0; i < 32; ++i) mx = fmaxf(mx, v[i]);
    #pragma unroll
    for (int off = 32; off > 0; off >>= 1) mx = fmaxf(mx, __shfl_xor(mx, off));

    float sum = 0.f;
    #pragma unroll
    for (int i = 0; i < 32; ++i) { v[i] = __expf(v[i] - mx); sum += v[i]; }
    #pragma unroll
    for (int off = 32; off > 0; off >>= 1) sum += __shfl_xor(sum, off);
    float inv = 1.0f / sum;

    #pragma unroll
    for (int c = 0; c < 4; ++c) {
        bf16x8 x;
        #pragma unroll
        for (int e = 0; e < 8; ++e) x[e] = (short)f2bf(v[c * 8 + e] * inv);
        *(bf16x8*)&S[base + c * 512 + lane * 8] = x;
    }
}

extern "C" void kernel_launch(void* const* d_in, const int* in_sizes, int n_in,
                              void* d_out, int out_size, void* d_ws, size_t ws_size,
                              hipStream_t stream)
{
    const float* x  = (const float*)d_in[0];
    const float* Wq = (const float*)d_in[1];
    const float* Wk = (const float*)d_in[2];
    const float* Wv = (const float*)d_in[3];
    float* out = (float*)d_out;

    // workspace layout (bf16 shorts)
    short* xb  = (short*)d_ws;                     // 16384*512
    short* wqb = xb  + (size_t)MTOT * DV;          // [Wq|Wk|Wv] contiguous = W_all[1536][512]
    short* wkb = wqb + (size_t)DA * DV;
    short* wvb = wkb + (size_t)DA * DV;
    short* Qb  = wvb + (size_t)DV * DV;            // 16384*512
    short* Kb  = Qb  + (size_t)MTOT * DA;
    short* VT  = Kb  + (size_t)MTOT * DA;          // [B][512][2048]
    short* Sc  = VT  + (size_t)MTOT * DV;          // 8*2048*2048

    const float qscale = 0.04419417382415922f;     // 1/sqrt(512)

    // 1) convert inputs to bf16
    cvt_f32_bf16<<<8192, 256, 0, stream>>>(x,  xb,  (MTOT * DV) / 4);
    cvt_f32_bf16<<<256,  256, 0, stream>>>(Wq, wqb, (DA * DV) / 4);
    cvt_f32_bf16<<<256,  256, 0, stream>>>(Wk, wkb, (DA * DV) / 4);
    cvt_f32_bf16<<<256,  256, 0, stream>>>(Wv, wvb, (DV * DV) / 4);

    // allow 128 KB dynamic LDS
    hipFuncSetAttribute(reinterpret_cast<const void*>(&gemm256<3>),
                        hipFuncAttributeMaxDynamicSharedMemorySize, 131072);
    hipFuncSetAttribute(reinterpret_cast<const void*>(&gemm256<0>),
                        hipFuncAttributeMaxDynamicSharedMemorySize, 131072);
    hipFuncSetAttribute(reinterpret_cast<const void*>(&gemm256<1>),
                        hipFuncAttributeMaxDynamicSharedMemorySize, 131072);

    // 2) fused QKV projection: M=16384, N=1536, K=512 -> Qb/Kb/VT
    gemm256<3><<<dim3(6 * 64, 1, 1), 512, 131072, stream>>>(
        xb, wqb, Qb, 6, DV, DV, DV, 0, 0, 0, 0, qscale);

    // 3) scores: per batch 2048x2048x512, bf16 out (Q pre-scaled)
    gemm256<0><<<dim3(8 * 8, 1, BQ), 512, 131072, stream>>>(
        Qb, Kb, Sc, 8, DA, DA, DA, SEQ,
        (long)SEQ * DA, (long)SEQ * DA, (long)SEQ * SEQ, 1.0f);

    // 4) softmax rows (in place on Sc)
    softmax_rows<<<(BQ * SEQ) / 4, 256, 0, stream>>>(Sc);

    // 5) PV: per batch 2048x512x2048, f32 out -> d_out
    gemm256<1><<<dim3(2 * 8, 1, BQ), 512, 131072, stream>>>(
        Sc, VT, out, 2, SEQ, SEQ, SEQ, DV,
        (long)SEQ * SEQ, (long)DV * SEQ, (long)SEQ * DV, 1.0f);
}

// Round 5
// 278.448 us; speedup vs baseline: 1.0121x; 1.0121x over previous
//
#include <hip/hip_runtime.h>
#include <hip/hip_bf16.h>
#include <math.h>

// Problem sizes (fixed by the reference)
#define BQ   8
#define SEQ  2048
#define DV   512
#define DA   512
#define MTOT (BQ * SEQ)   // 16384

typedef __attribute__((ext_vector_type(8))) short bf16x8;
typedef __attribute__((ext_vector_type(4))) float f32x4;
typedef __attribute__((ext_vector_type(4))) short short4v;

__device__ __forceinline__ unsigned short f2bf(float f) {
    union { float f; unsigned u; } c; c.f = f;
    unsigned u = c.u;
    unsigned r = (u + 0x7fffu + ((u >> 16) & 1u)) >> 16;
    return (unsigned short)r;
}
__device__ __forceinline__ float bf2f(unsigned short h) {
    union { unsigned u; float f; } c; c.u = ((unsigned)h) << 16;
    return c.f;
}

__device__ __forceinline__ void gload_lds16(const void* g, void* l) {
    __builtin_amdgcn_global_load_lds(
        (const __attribute__((address_space(1))) void*)g,
        (__attribute__((address_space(3))) void*)l,
        16, 0, 0);
}

// inline-asm LDS read: opaque to the compiler's waitcnt insertion, so no
// conservative vmcnt(0) drain is emitted against in-flight global_load_lds.
__device__ __forceinline__ bf16x8 dsr128(const short* p) {
    bf16x8 r;
    asm volatile("ds_read_b128 %0, %1"
                 : "=v"(r)
                 : "v"((const __attribute__((address_space(3))) short*)p));
    return r;
}

// inline-asm barrier: the waitcnt pass inserts vmcnt(0) before a *visible*
// s_barrier when LDS-DMA (global_load_lds) is pending — that drain was the
// per-phase stall. Hiding the barrier keeps our counted vmcnt(N) authoritative.
__device__ __forceinline__ void barx() {
    __builtin_amdgcn_sched_barrier(0);
    asm volatile("s_barrier");
    __builtin_amdgcn_sched_barrier(0);
}

// ---------------- convert f32 -> bf16 (vectorized) ----------------
__global__ __launch_bounds__(256) void cvt_f32_bf16(
    const float* __restrict__ in, short* __restrict__ out, int n4)
{
    int i = blockIdx.x * blockDim.x + threadIdx.x;
    int stride = gridDim.x * blockDim.x;
    for (; i < n4; i += stride) {
        float4 v = ((const float4*)in)[i];
        short4v o;
        o[0] = (short)f2bf(v.x);
        o[1] = (short)f2bf(v.y);
        o[2] = (short)f2bf(v.z);
        o[3] = (short)f2bf(v.w);
        ((short4v*)out)[i] = o;
    }
}

// =====================================================================
// 256x256x(BK=64) 8-phase bf16 GEMM (T2 swizzle + T3/T4 counted vmcnt + T5)
// C[M,N] = A[M,K] * B[N,K]^T, fp32 accum. 512 threads = 8 waves (2Mx4N),
// per-wave 128x64 output = acc[8][4] of 16x16 frags. LDS 128 KB.
// ds-reads, waits, and barriers are inline-asm (rule #18 pattern).
// OMODE 0: bf16 C row-major (batched)     [scores]
// OMODE 1: f32  C row-major (batched)     [PV -> d_out]
// OMODE 3: fused QKV epilogue: col<512 -> Q (scaled), <1024 -> K, else V^T
// =====================================================================
template<int OMODE>
__global__ __launch_bounds__(512, 2) void gemm256(
    const short* __restrict__ A, const short* __restrict__ B, void* __restrict__ Cv,
    int ntx, int K, int lda, int ldb, int ldc,
    long strideA, long strideB, long strideC, float scale)
{
    extern __shared__ short lds[];
    short* const bufA0 = lds;
    short* const bufA1 = lds + 16384;
    short* const bufB0 = lds + 32768;
    short* const bufB1 = lds + 49152;

    const int tid  = threadIdx.x;
    const int lane = tid & 63;
    const int wv   = tid >> 6;
    const int wr   = wv >> 2;    // 0..1
    const int wc   = wv & 3;     // 0..3
    const int r16  = lane & 15;
    const int kq   = lane >> 4;  // 0..3
    const int swz  = (r16 & 7) * 8;                 // shorts (== 16B-granule XOR)
    const int cs[2] = { (kq * 8) ^ swz, (32 + kq * 8) ^ swz };
    const int aOff = (wr * 128 + r16) * 64;         // shorts into A tile
    const int bOff = (wc * 64  + r16) * 64;         // shorts into B tile

    // bijective XCD swizzle (m204)
    const int nwg = gridDim.x;
    const int wg  = blockIdx.x;
    const int q8  = nwg >> 3, r8 = nwg & 7;
    const int xcd = wg & 7, off8 = wg >> 3;
    const int swg = (xcd < r8 ? xcd * (q8 + 1) : r8 * (q8 + 1) + (xcd - r8) * q8) + off8;
    const int tx = swg % ntx, ty = swg / ntx;
    const int brow = ty * 256, bcol = tx * 256;
    const int z = blockIdx.z;

    A += (size_t)z * strideA + (size_t)brow * lda;
    B += (size_t)z * strideB + (size_t)bcol * ldb;

    // stage one half-tile (128 rows x 64 cols bf16 = 16KB) : 2 loads/thread
    auto stageHalf = [&](const short* gbase, int ld, short* region, int h) {
        #pragma unroll
        for (int c = 0; c < 2; ++c) {
            int s    = h * 1024 + c * 512 + tid;   // 16B slot index 0..2047
            int row  = s >> 3;
            int chnk = (s & 7) ^ (row & 7);        // inverse-swizzled source
            gload_lds16(gbase + (size_t)row * ld + chnk * 8, region + s * 8);
        }
    };

    f32x4 acc[8][4];
    const f32x4 fz = {0.f, 0.f, 0.f, 0.f};
    #pragma unroll
    for (int i = 0; i < 8; ++i)
        #pragma unroll
        for (int j = 0; j < 4; ++j) acc[i][j] = fz;

    bf16x8 af[4][2], bfr[4][2];

    auto dsA = [&](const short* base, int ibase) {
        #pragma unroll
        for (int i = 0; i < 4; ++i)
            #pragma unroll
            for (int kk = 0; kk < 2; ++kk)
                af[i][kk] = dsr128(base + aOff + (ibase + i) * 1024 + cs[kk]);
    };
    auto dsB = [&](const short* base, int jbase) {
        #pragma unroll
        for (int j = 0; j < 2; ++j)
            #pragma unroll
            for (int kk = 0; kk < 2; ++kk)
                bfr[jbase + j][kk] = dsr128(base + bOff + (jbase + j) * 1024 + cs[kk]);
    };
    auto doQ = [&](int ibase, int jbase) {
        __builtin_amdgcn_s_setprio(1);
        #pragma unroll
        for (int i = 0; i < 4; ++i)
            #pragma unroll
            for (int j = 0; j < 2; ++j)
                #pragma unroll
                for (int kk = 0; kk < 2; ++kk)
                    acc[ibase + i][jbase + j] = __builtin_amdgcn_mfma_f32_16x16x32_bf16(
                        af[i][kk], bfr[jbase + j][kk], acc[ibase + i][jbase + j], 0, 0, 0);
        __builtin_amdgcn_s_setprio(0);
    };

    const int NT = K >> 6;   // K-tiles of 64 (NT even, >= 4 for all our shapes)

    // ---- prologue: B(0), A(0), B(1) staged; keep B(1) in flight
    stageHalf(B,      ldb, bufB0, 0);  stageHalf(B,      ldb, bufB0, 1);
    stageHalf(A,      lda, bufA0, 0);  stageHalf(A,      lda, bufA0, 1);
    stageHalf(B + 64, ldb, bufB1, 0);  stageHalf(B + 64, ldb, bufB1, 1);
    asm volatile("s_waitcnt vmcnt(4)");
    barx();

    for (int t = 0; t < NT; t += 2) {
        const bool s2 = (t + 2) < NT;      // tile t+2 exists
        const bool s3 = (t + 3) < NT;      // tile t+3 exists
        const short* At1 = A + (t + 1) * 64;
        const short* At2 = A + (t + 2) * 64;
        const short* Bt2 = B + (t + 2) * 64;
        const short* Bt3 = B + (t + 3) * 64;

        // ph1: Q0 of tile t (m0-3 x n0-1)
        dsA(bufA0, 0); dsB(bufB0, 0);
        stageHalf(At1, lda, bufA1, 0);
        barx();
        asm volatile("s_waitcnt lgkmcnt(0)");
        __builtin_amdgcn_sched_barrier(0);
        doQ(0, 0);
        barx();

        // ph2: Q1 (m0-3 x n2-3)
        dsB(bufB0, 2);
        stageHalf(At1, lda, bufA1, 1);
        barx();
        asm volatile("s_waitcnt lgkmcnt(0)");
        __builtin_amdgcn_sched_barrier(0);
        doQ(0, 2);
        barx();

        // ph3: Q2 (m4-7 x n0-1)
        dsA(bufA0, 4);
        if (s2) stageHalf(Bt2, ldb, bufB0, 0);
        barx();
        asm volatile("s_waitcnt lgkmcnt(0)");
        __builtin_amdgcn_sched_barrier(0);
        doQ(4, 0);
        barx();

        // ph4: Q3 (m4-7 x n2-3); counted vmcnt
        if (s2) stageHalf(Bt2, ldb, bufB0, 1);
        if (s2) asm volatile("s_waitcnt vmcnt(4)");
        else    asm volatile("s_waitcnt vmcnt(0)");
        __builtin_amdgcn_sched_barrier(0);
        barx();
        doQ(4, 2);
        barx();

        // ph5: tile t+1, Q0
        dsA(bufA1, 0); dsB(bufB1, 0);
        if (s2) stageHalf(At2, lda, bufA0, 0);
        barx();
        asm volatile("s_waitcnt lgkmcnt(0)");
        __builtin_amdgcn_sched_barrier(0);
        doQ(0, 0);
        barx();

        // ph6: Q1
        dsB(bufB1, 2);
        if (s2) stageHalf(At2, lda, bufA0, 1);
        barx();
        asm volatile("s_waitcnt lgkmcnt(0)");
        __builtin_amdgcn_sched_barrier(0);
        doQ(0, 2);
        barx();

        // ph7: Q2
        dsA(bufA1, 4);
        if (s3) stageHalf(Bt3, ldb, bufB1, 0);
        barx();
        asm volatile("s_waitcnt lgkmcnt(0)");
        __builtin_amdgcn_sched_barrier(0);
        doQ(4, 0);
        barx();

        // ph8: Q3; counted vmcnt
        if (s3) stageHalf(Bt3, ldb, bufB1, 1);
        if (s3) asm volatile("s_waitcnt vmcnt(4)");
        else    asm volatile("s_waitcnt vmcnt(0)");
        __builtin_amdgcn_sched_barrier(0);
        barx();
        doQ(4, 2);
        barx();
    }

    // ---- epilogue
    const int orow = (lane >> 4) * 4;
    #pragma unroll
    for (int i = 0; i < 8; ++i) {
        int grow = brow + wr * 128 + i * 16 + orow;
        #pragma unroll
        for (int j = 0; j < 4; ++j) {
            int gcol = bcol + wc * 64 + j * 16 + r16;
            f32x4 v = acc[i][j];
            #pragma unroll
            for (int tt = 0; tt < 4; ++tt) {
                int row = grow + tt;
                if (OMODE == 0) {
                    ((short*)Cv)[(size_t)z * strideC + (size_t)row * ldc + gcol] =
                        (short)f2bf(v[tt] * scale);
                } else if (OMODE == 1) {
                    ((float*)Cv)[(size_t)z * strideC + (size_t)row * ldc + gcol] = v[tt];
                } else { // OMODE 3: fused QKV
                    short* Qb = (short*)Cv;
                    short* Kb = Qb + (size_t)MTOT * DA;
                    short* VT = Kb + (size_t)MTOT * DA;
                    if (gcol < 512) {
                        Qb[(size_t)row * DA + gcol] = (short)f2bf(v[tt] * scale);
                    } else if (gcol < 1024) {
                        Kb[(size_t)row * DA + (gcol - 512)] = (short)f2bf(v[tt]);
                    } else {
                        int vcol = gcol - 1024;
                        int bb = row >> 11, ss = row & (SEQ - 1);
                        VT[((size_t)bb * DV + vcol) * SEQ + ss] = (short)f2bf(v[tt]);
                    }
                }
            }
        }
    }
}

// ---------------- row softmax over 2048 bf16, in place, 1 wave / row ------
__global__ __launch_bounds__(256) void softmax_rows(short* __restrict__ S)
{
    int row  = blockIdx.x * 4 + (threadIdx.x >> 6);
    int lane = threadIdx.x & 63;
    size_t base = (size_t)row * SEQ;

    float v[32];
    #pragma unroll
    for (int c = 0; c < 4; ++c) {
        bf16x8 x = *(const bf16x8*)&S[base + c * 512 + lane * 8];
        #pragma unroll
        for (int e = 0; e < 8; ++e) v[c * 8 + e] = bf2f((unsigned short)x[e]);
    }
    float mx = -1e30f;
    #pragma unroll
    for (int i = 0; i < 32; ++i) mx = fmaxf(mx, v[i]);
    #pragma unroll
    for (int off = 32; off > 0; off >>= 1) mx = fmaxf(mx, __shfl_xor(mx, off));

    float sum = 0.f;
    #pragma unroll
    for (int i = 0; i < 32; ++i) { v[i] = __expf(v[i] - mx); sum += v[i]; }
    #pragma unroll
    for (int off = 32; off > 0; off >>= 1) sum += __shfl_xor(sum, off);
    float inv = 1.0f / sum;

    #pragma unroll
    for (int c = 0; c < 4; ++c) {
        bf16x8 x;
        #pragma unroll
        for (int e = 0; e < 8; ++e) x[e] = (short)f2bf(v[c * 8 + e] * inv);
        *(bf16x8*)&S[base + c * 512 + lane * 8] = x;
    }
}

extern "C" void kernel_launch(void* const* d_in, const int* in_sizes, int n_in,
                              void* d_out, int out_size, void* d_ws, size_t ws_size,
                              hipStream_t stream)
{
    const float* x  = (const float*)d_in[0];
    const float* Wq = (const float*)d_in[1];
    const float* Wk = (const float*)d_in[2];
    const float* Wv = (const float*)d_in[3];
    float* out = (float*)d_out;

    // workspace layout (bf16 shorts)
    short* xb  = (short*)d_ws;                     // 16384*512
    short* wqb = xb  + (size_t)MTOT * DV;          // [Wq|Wk|Wv] contiguous = W_all[1536][512]
    short* wkb = wqb + (size_t)DA * DV;
    short* wvb = wkb + (size_t)DA * DV;
    short* Qb  = wvb + (size_t)DV * DV;            // 16384*512
    short* Kb  = Qb  + (size_t)MTOT * DA;
    short* VT  = Kb  + (size_t)MTOT * DA;          // [B][512][2048]
    short* Sc  = VT  + (size_t)MTOT * DV;          // 8*2048*2048

    const float qscale = 0.04419417382415922f;     // 1/sqrt(512)

    // 1) convert inputs to bf16
    cvt_f32_bf16<<<8192, 256, 0, stream>>>(x,  xb,  (MTOT * DV) / 4);
    cvt_f32_bf16<<<256,  256, 0, stream>>>(Wq, wqb, (DA * DV) / 4);
    cvt_f32_bf16<<<256,  256, 0, stream>>>(Wk, wkb, (DA * DV) / 4);
    cvt_f32_bf16<<<256,  256, 0, stream>>>(Wv, wvb, (DV * DV) / 4);

    // allow 128 KB dynamic LDS
    hipFuncSetAttribute(reinterpret_cast<const void*>(&gemm256<3>),
                        hipFuncAttributeMaxDynamicSharedMemorySize, 131072);
    hipFuncSetAttribute(reinterpret_cast<const void*>(&gemm256<0>),
                        hipFuncAttributeMaxDynamicSharedMemorySize, 131072);
    hipFuncSetAttribute(reinterpret_cast<const void*>(&gemm256<1>),
                        hipFuncAttributeMaxDynamicSharedMemorySize, 131072);

    // 2) fused QKV projection: M=16384, N=1536, K=512 -> Qb/Kb/VT
    gemm256<3><<<dim3(6 * 64, 1, 1), 512, 131072, stream>>>(
        xb, wqb, Qb, 6, DV, DV, DV, 0, 0, 0, 0, qscale);

    // 3) scores: per batch 2048x2048x512, bf16 out (Q pre-scaled)
    gemm256<0><<<dim3(8 * 8, 1, BQ), 512, 131072, stream>>>(
        Qb, Kb, Sc, 8, DA, DA, DA, SEQ,
        (long)SEQ * DA, (long)SEQ * DA, (long)SEQ * SEQ, 1.0f);

    // 4) softmax rows (in place on Sc)
    softmax_rows<<<(BQ * SEQ) / 4, 256, 0, stream>>>(Sc);

    // 5) PV: per batch 2048x512x2048, f32 out -> d_out
    gemm256<1><<<dim3(2 * 8, 1, BQ), 512, 131072, stream>>>(
        Sc, VT, out, 2, SEQ, SEQ, SEQ, DV,
        (long)SEQ * SEQ, (long)DV * SEQ, (long)SEQ * DV, 1.0f);
}